// Round 6
// baseline (368.503 us; speedup 1.0000x reference)
//
#include <hip/hip_runtime.h>
#include <hip/hip_bf16.h>

typedef unsigned int u32;
typedef unsigned short u16;
typedef __attribute__((ext_vector_type(8))) short short8;   // 8 bf16 (4 VGPRs)
typedef __attribute__((ext_vector_type(4))) float f32x4;    // MFMA C/D

#define N_PTS 100000
#define NSAMP 16

__device__ __forceinline__ float lo2f(u32 u){ return __uint_as_float(u << 16); }
__device__ __forceinline__ float hi2f(u32 u){ return __uint_as_float(u & 0xffff0000u); }
__device__ __forceinline__ float us2f(u16 u){ return __uint_as_float(((u32)u) << 16); }

// round-to-nearest-even f32 -> bf16 bits (finite values only)
__device__ __forceinline__ u16 f2bf(float f) {
    u32 u = __float_as_uint(f);
    return (u16)((u + 0x7fffu + ((u >> 16) & 1u)) >> 16);
}
__device__ __forceinline__ u32 pack2(float k, float v) {
    return (u32)f2bf(k) | ((u32)f2bf(v) << 16);
}

// wave-local LDS RAW fence: waits for this wave's outstanding DS ops.
// Valid ONLY because every LDS buffer slice is owned by a single wave.
#define WAVE_LDS_FENCE() asm volatile("s_waitcnt lgkmcnt(0)" ::: "memory")

// Runtime input-dtype probe (must be called by ALL threads of the block).
__device__ __forceinline__ bool detect_f32(const u16* __restrict__ xprobe) {
    float f = us2f(xprobe[(threadIdx.x & 63) * 2]);
    int cnt = __syncthreads_count(fabsf(f) > 1024.0f ? 1 : 0);
    return cnt >= 8;
}

// canonical fp32 weight-block offsets (floats, each 16B-aligned)
#define OFF_WQ   0
#define OFF_BQ   4096
#define OFF_WK   4160
#define OFF_BK   8256
#define OFF_WV   8320
#define OFF_BV   12416
#define OFF_WP1  12480
#define OFF_BP1  12492
#define OFF_GP   12496
#define OFF_BP   12500
#define OFF_WP2  12504
#define OFF_BP2  12696
#define OFF_G1   12760
#define OFF_BB1  12824
#define OFF_WA   12888
#define OFF_BA   13400
#define OFF_G2   13408
#define OFF_BB2  13416
#define OFF_WB   13424
#define OFF_BW   13488
#define FRAG_OFF 13504   /* bf16 frag blob: 2 planes x 12288 u16 = 12288 floats */
#define OFF_WAT  25792   /* WaT[s][c] : 8 x 64 f32 (transposed Wa)  */
#define OFF_WBT  26304   /* WbT[t][s] : 8 x 8  f32 (transposed Wb)  */
#define CW_PAD   32768   /* pad region to 128 KB of floats */

// ---------------------------------------------------------------------------
// K0: canonicalize weights to fp32 + build pre-transposed bf16 hi/lo MFMA
// B-fragment blob (for QKV) + WaT/WbT fp32 transposed blobs (for attn).
// ---------------------------------------------------------------------------
__global__ __launch_bounds__(256) void convert_kernel(
    const u16* __restrict__ xprobe,
    const void* s0,  const void* s1,  const void* s2,  const void* s3,
    const void* s4,  const void* s5,  const void* s6,  const void* s7,
    const void* s8,  const void* s9,  const void* s10, const void* s11,
    const void* s12, const void* s13, const void* s14, const void* s15,
    const void* s16, const void* s17, const void* s18, const void* s19,
    float* __restrict__ cw)
{
    bool isf32 = detect_f32(xprobe);
    const void* srcs[20] = {s0,s1,s2,s3,s4,s5,s6,s7,s8,s9,s10,s11,s12,s13,s14,s15,s16,s17,s18,s19};
    const int sizes[20] = {4096,64,4096,64,4096,64,9,3,3,3,192,64,64,64,512,8,8,8,64,8};
    const int offs[20]  = {OFF_WQ,OFF_BQ,OFF_WK,OFF_BK,OFF_WV,OFF_BV,OFF_WP1,OFF_BP1,OFF_GP,OFF_BP,
                           OFF_WP2,OFF_BP2,OFF_G1,OFF_BB1,OFF_WA,OFF_BA,OFF_G2,OFF_BB2,OFF_WB,OFF_BW};
    int tid = threadIdx.x + blockIdx.x * 256;
    int stride = gridDim.x * 256;
    for (int a = 0; a < 20; a++) {
        const void* s = srcs[a];
        for (int k = tid; k < sizes[a]; k += stride)
            cw[offs[a] + k] = isf32 ? ((const float*)s)[k] : us2f(((const u16*)s)[k]);
    }

    // MFMA B-frag blob (reads raw weight srcs directly)
    u16* fb = (u16*)(cw + FRAG_OFF);
    for (int t = tid; t < 24576; t += stride) {
        int plane = t / 12288, r = t - plane * 12288;
        int m  = r >> 12;
        int r2 = r & 4095;
        int kh = r2 >> 11;
        int r3 = r2 & 2047;
        int w  = r3 >> 9;
        int r4 = r3 & 511;
        int l  = r4 >> 3, j = r4 & 7;
        int k  = kh * 32 + (l >> 4) * 8 + j;
        int nc = w * 16 + (l & 15);
        int si = k * 64 + nc;
        const void* s = (m == 0) ? s0 : ((m == 1) ? s2 : s4);
        float val = isf32 ? ((const float*)s)[si] : us2f(((const u16*)s)[si]);
        u16 hb = f2bf(val);
        fb[t] = (plane == 0) ? hb : f2bf(val - us2f(hb));
    }

    // WaT[s][c] = Wa[c][s] ; WbT[t][s] = Wb[s][t]
    for (int t = tid; t < 512 + 64; t += stride) {
        if (t < 512) {
            int s = t >> 6, cc = t & 63;
            int si = cc * 8 + s;
            cw[OFF_WAT + s * 64 + cc] = isf32 ? ((const float*)s14)[si] : us2f(((const u16*)s14)[si]);
        } else {
            int r = t - 512;
            int tt = r >> 3, ss = r & 7;
            int si = ss * 8 + tt;
            cw[OFF_WBT + tt * 8 + ss] = isf32 ? ((const float*)s18)[si] : us2f(((const u16*)s18)[si]);
        }
    }
}

// ---------------------------------------------------------------------------
// K1: MFMA QKV projection (unchanged from round 4 — passing).
// ---------------------------------------------------------------------------
#define QKV_TPB 5
__global__ __launch_bounds__(256) void qkv_mfma_kernel(
    const u16* __restrict__ xraw, const float* __restrict__ cw,
    float* __restrict__ Q, u32* __restrict__ KV)
{
    bool isf32 = detect_f32(xraw);
    const int w   = threadIdx.x >> 6;
    const int l   = threadIdx.x & 63;
    const int col = l & 15;
    const int g   = l >> 4;

    const u16* fbh = (const u16*)(cw + FRAG_OFF);
    const u16* fbl = fbh + 12288;
    short8 bh[3][2], bl[3][2];
#pragma unroll
    for (int m = 0; m < 3; m++)
#pragma unroll
        for (int kh = 0; kh < 2; kh++) {
            int o = (((m * 2 + kh) * 4 + w) * 64 + l) * 8;
            bh[m][kh] = *(const short8*)(fbh + o);
            bl[m][kh] = *(const short8*)(fbl + o);
        }
    const float bqc = cw[OFF_BQ + w * 16 + col];
    const float bkc = cw[OFF_BK + w * 16 + col];
    const float bvc = cw[OFF_BV + w * 16 + col];

#define LOAD_A(IT, AH, AL)                                                        \
    {                                                                             \
        const int M0_ = (blockIdx.x * QKV_TPB + (IT)) * 16;                       \
        if (isf32) {                                                              \
            const float4* xf = (const float4*)xraw;                               \
            _Pragma("unroll")                                                     \
            for (int kh = 0; kh < 2; kh++) {                                      \
                float4 f0 = xf[(size_t)(M0_ + col) * 16 + kh * 8 + g * 2];        \
                float4 f1 = xf[(size_t)(M0_ + col) * 16 + kh * 8 + g * 2 + 1];    \
                float ff[8] = {f0.x, f0.y, f0.z, f0.w, f1.x, f1.y, f1.z, f1.w};   \
                _Pragma("unroll")                                                 \
                for (int j = 0; j < 8; j++) {                                     \
                    u16 hb_ = f2bf(ff[j]);                                        \
                    AH[kh][j] = (short)hb_;                                       \
                    AL[kh][j] = (short)f2bf(ff[j] - us2f(hb_));                   \
                }                                                                 \
            }                                                                     \
        } else {                                                                  \
            const short8* xb = (const short8*)xraw;                               \
            _Pragma("unroll")                                                     \
            for (int kh = 0; kh < 2; kh++)                                        \
                AH[kh] = xb[(size_t)(M0_ + col) * 8 + kh * 4 + g];                \
        }                                                                         \
    }

    short8 ahA[2], alA[2], ahB[2], alB[2];
    LOAD_A(0, ahA, alA);

#pragma unroll
    for (int it = 0; it < QKV_TPB; it++) {
        short8 (&ah)[2] = (it & 1) ? ahB : ahA;
        short8 (&al)[2] = (it & 1) ? alB : alA;
        short8 (&ahN)[2] = (it & 1) ? ahA : ahB;
        short8 (&alN)[2] = (it & 1) ? alA : alB;
        if (it + 1 < QKV_TPB) LOAD_A(it + 1, ahN, alN);

        const int M0 = (blockIdx.x * QKV_TPB + it) * 16;
        f32x4 aQ = {bqc, bqc, bqc, bqc};
        f32x4 aK = {bkc, bkc, bkc, bkc};
        f32x4 aV = {bvc, bvc, bvc, bvc};

#pragma unroll
        for (int kh = 0; kh < 2; kh++) {
            aQ = __builtin_amdgcn_mfma_f32_16x16x32_bf16(ah[kh], bh[0][kh], aQ, 0, 0, 0);
            aK = __builtin_amdgcn_mfma_f32_16x16x32_bf16(ah[kh], bh[1][kh], aK, 0, 0, 0);
            aV = __builtin_amdgcn_mfma_f32_16x16x32_bf16(ah[kh], bh[2][kh], aV, 0, 0, 0);
            aQ = __builtin_amdgcn_mfma_f32_16x16x32_bf16(ah[kh], bl[0][kh], aQ, 0, 0, 0);
            aK = __builtin_amdgcn_mfma_f32_16x16x32_bf16(ah[kh], bl[1][kh], aK, 0, 0, 0);
            aV = __builtin_amdgcn_mfma_f32_16x16x32_bf16(ah[kh], bl[2][kh], aV, 0, 0, 0);
            if (isf32) {
                aQ = __builtin_amdgcn_mfma_f32_16x16x32_bf16(al[kh], bh[0][kh], aQ, 0, 0, 0);
                aK = __builtin_amdgcn_mfma_f32_16x16x32_bf16(al[kh], bh[1][kh], aK, 0, 0, 0);
                aV = __builtin_amdgcn_mfma_f32_16x16x32_bf16(al[kh], bh[2][kh], aV, 0, 0, 0);
            }
        }

#pragma unroll
        for (int r = 0; r < 4; r++) {
            int row = M0 + g * 4 + r;
            Q [(size_t)row * 64 + w * 16 + col] = aQ[r];
            KV[(size_t)row * 64 + w * 16 + col] = pack2(aK[r], aV[r]);
        }
    }
#undef LOAD_A
}

// ---------------------------------------------------------------------------
// K2: fused attention — BARRIER-FREE. Every LDS buffer is indexed [pt] and
// owned exclusively by wave pt, so all 4 __syncthreads are replaced with
// wave-local s_waitcnt lgkmcnt(0) fences (primitive validated in round 4).
// Waves now progress independently -> random-gather latency of one point no
// longer convoys the other three.
// Also: stage 2/3 reps merged (same s per lane), Wa/Wb read as float4 from
// pre-transposed blobs (16+2 vector loads vs 144 scalar), stage-3 logits
// kept in registers straight into the shfl_xor softmax.
// ---------------------------------------------------------------------------
__global__ __launch_bounds__(256) void attn_kernel(
    const u16* __restrict__ P, const int* __restrict__ IDX,
    const u16* __restrict__ xprobe, const float* __restrict__ cw,
    const float* __restrict__ Q, const u32* __restrict__ KV,
    void* __restrict__ OUT)
{
    __shared__ __align__(16) float wvbuf[4][NSAMP * 68];  // relu(bn1(w)), stride 68
    __shared__ __align__(16) float tbbuf[4][NSAMP * 8];   // relu(bn2(.@Wa+ba))
    __shared__ __align__(16) float w2buf[4][NSAMP * 8];   // softmax weights
    __shared__ __align__(16) float hbuf[4][NSAMP * 4];    // h[n][d], d<3 used

    bool isf32 = detect_f32(xprobe);

    const int pt = threadIdx.x >> 6;
    const int c  = threadIdx.x & 63;
    const int i  = blockIdx.x * 4 + pt;        // grid*4 == N_PTS exactly
    const float rs = 1.0f / sqrtf(1.0f + 1e-5f);

    // ---- neighbor indices (lane n<16 holds j_n), then all 16 gathers ----
    const int jv = IDX[(size_t)i * NSAMP + (c & 15)];

    u32 kvw[NSAMP];
    const u32* KVc = KV + c;
#pragma unroll
    for (int n = 0; n < NSAMP; n++) {
        int j = __builtin_amdgcn_readlane(jv, n);   // SGPR -> SALU addressing
        kvw[n] = KVc[(size_t)j << 6];
    }

    const float qq = Q[(size_t)i * 64 + c];

    // ---- distributed h-MLP: lane (n,d) = (c/3, c%3) computes h[n][d] ----
    const float* Pf = (const float*)P;
    const int n_p  = c / 3;
    const int d_p  = c - n_p * 3;
    const int np15 = n_p & 15;
    const int j_p  = __shfl(jv, np15, 64);
    float pj, pid;
    if (isf32) { pj = Pf[(size_t)j_p * 3 + d_p]; pid = Pf[(size_t)i * 3 + d_p]; }
    else       { pj = us2f(P[(size_t)j_p * 3 + d_p]); pid = us2f(P[(size_t)i * 3 + d_p]); }
    const float pr = pj - pid;
    const int lb = np15 * 3;
    const float prD0 = __shfl(pr, lb + 0, 64);
    const float prD1 = __shfl(pr, lb + 1, 64);
    const float prD2 = __shfl(pr, lb + 2, 64);
    {
        float gd  = cw[OFF_GP + d_p] * rs;
        float w0s = cw[OFF_WP1 + 0 * 3 + d_p] * gd;
        float w1s = cw[OFF_WP1 + 1 * 3 + d_p] * gd;
        float w2s = cw[OFF_WP1 + 2 * 3 + d_p] * gd;
        float bs  = cw[OFF_BP1 + d_p] * gd + cw[OFF_BP + d_p];
        float h = fmaf(prD2, w2s, fmaf(prD1, w1s, fmaf(prD0, w0s, bs)));
        h = fmaxf(h, 0.0f);
        if (c < 48) hbuf[pt][np15 * 4 + d_p] = h;
    }
    WAVE_LDS_FENCE();   // hbuf RAW (same wave)

    // per-lane channel constants (loaded into regs before fences)
    const float wp2c0 = cw[OFF_WP2 + 0 * 64 + c];
    const float wp2c1 = cw[OFF_WP2 + 1 * 64 + c];
    const float wp2c2 = cw[OFF_WP2 + 2 * 64 + c];
    const float bp2c  = cw[OFF_BP2 + c];
    const float g1c   = cw[OFF_G1  + c] * rs;
    const float bb1c  = cw[OFF_BB1 + c];

    float pv[NSAMP];

    // ---- stage 1: per-(n,c) relation input into LDS; v+pe kept in regs ----
#pragma unroll
    for (int n = 0; n < NSAMP; n++) {
        float4 hb = *((const float4*)&hbuf[pt][n * 4]);
        float pe = fmaf(hb.z, wp2c2, fmaf(hb.y, wp2c1, fmaf(hb.x, wp2c0, bp2c)));
        float kk = lo2f(kvw[n]);
        float vv = hi2f(kvw[n]);
        wvbuf[pt][n * 68 + c] = fmaxf(fmaf(kk - qq + pe, g1c, bb1c), 0.0f);
        pv[n] = vv + pe;
    }
    WAVE_LDS_FENCE();   // wvbuf RAW (same wave)

    // ---- stage 2 (merged reps): lane owns (n, n+8) x s; Wa from WaT blob ----
    const int s2s = c & 7, s2n = c >> 3;
    float a0 = cw[OFF_BA + s2s], a1 = a0;
    const float4* waT4 = (const float4*)(cw + OFF_WAT + s2s * 64);
#pragma unroll
    for (int c4 = 0; c4 < 16; c4++) {
        float4 wa  = waT4[c4];
        float4 w40 = *((const float4*)&wvbuf[pt][s2n * 68 + c4 * 4]);
        float4 w41 = *((const float4*)&wvbuf[pt][(s2n + 8) * 68 + c4 * 4]);
        a0 = fmaf(w40.x, wa.x, a0); a0 = fmaf(w40.y, wa.y, a0);
        a0 = fmaf(w40.z, wa.z, a0); a0 = fmaf(w40.w, wa.w, a0);
        a1 = fmaf(w41.x, wa.x, a1); a1 = fmaf(w41.y, wa.y, a1);
        a1 = fmaf(w41.z, wa.z, a1); a1 = fmaf(w41.w, wa.w, a1);
    }
    {
        float g2s = cw[OFF_G2 + s2s] * rs, bb2s = cw[OFF_BB2 + s2s];
        tbbuf[pt][s2n * 8 + s2s]       = fmaxf(fmaf(a0, g2s, bb2s), 0.0f);
        tbbuf[pt][(s2n + 8) * 8 + s2s] = fmaxf(fmaf(a1, g2s, bb2s), 0.0f);
    }
    WAVE_LDS_FENCE();   // tbbuf RAW (same wave)

    // ---- stage 3 (merged reps): logits in registers; Wb from WbT blob ----
    float w2a = cw[OFF_BW + s2s], w2b = w2a;
    {
        float4 wb0 = *(const float4*)(cw + OFF_WBT + s2s * 8);
        float4 wb1 = *(const float4*)(cw + OFF_WBT + s2s * 8 + 4);
        float4 t00 = *((const float4*)&tbbuf[pt][s2n * 8]);
        float4 t01 = *((const float4*)&tbbuf[pt][s2n * 8 + 4]);
        float4 t10 = *((const float4*)&tbbuf[pt][(s2n + 8) * 8]);
        float4 t11 = *((const float4*)&tbbuf[pt][(s2n + 8) * 8 + 4]);
        w2a = fmaf(t00.x, wb0.x, w2a); w2a = fmaf(t00.y, wb0.y, w2a);
        w2a = fmaf(t00.z, wb0.z, w2a); w2a = fmaf(t00.w, wb0.w, w2a);
        w2a = fmaf(t01.x, wb1.x, w2a); w2a = fmaf(t01.y, wb1.y, w2a);
        w2a = fmaf(t01.z, wb1.z, w2a); w2a = fmaf(t01.w, wb1.w, w2a);
        w2b = fmaf(t10.x, wb0.x, w2b); w2b = fmaf(t10.y, wb0.y, w2b);
        w2b = fmaf(t10.z, wb0.z, w2b); w2b = fmaf(t10.w, wb0.w, w2b);
        w2b = fmaf(t11.x, wb1.x, w2b); w2b = fmaf(t11.y, wb1.y, w2b);
        w2b = fmaf(t11.z, wb1.z, w2b); w2b = fmaf(t11.w, wb1.w, w2b);
    }

    // ---- stage 4: softmax over n per channel t, straight from registers ----
    {
        float m = fmaxf(w2a, w2b);
        m = fmaxf(m, __shfl_xor(m, 8, 64));
        m = fmaxf(m, __shfl_xor(m, 16, 64));
        m = fmaxf(m, __shfl_xor(m, 32, 64));
        float e0 = __expf(w2a - m), e1 = __expf(w2b - m);
        float s = e0 + e1;
        s += __shfl_xor(s, 8, 64);
        s += __shfl_xor(s, 16, 64);
        s += __shfl_xor(s, 32, 64);
        float inv = 1.0f / s;
        w2buf[pt][s2n * 8 + s2s]       = e0 * inv;
        w2buf[pt][(s2n + 8) * 8 + s2s] = e1 * inv;
    }
    WAVE_LDS_FENCE();   // w2buf RAW (same wave)

    // ---- stage 5: out[c] = sum_n pv[n] * w[n][c&7] ----
    float o = 0.0f;
#pragma unroll
    for (int n = 0; n < NSAMP; n++)
        o = fmaf(pv[n], w2buf[pt][n * 8 + s2s], o);
    if (isf32) ((float*)OUT)[(size_t)i * 64 + c] = o;
    else       ((__hip_bfloat16*)OUT)[(size_t)i * 64 + c] = __float2bfloat16(o);
}

// ---------------------------------------------------------------------------
extern "C" void kernel_launch(void* const* d_in, const int* in_sizes, int n_in,
                              void* d_out, int out_size, void* d_ws, size_t ws_size,
                              hipStream_t stream)
{
    const u16* p   = (const u16*)d_in[0];
    const u16* x   = (const u16*)d_in[1];
    const int* idx = (const int*)d_in[2];

    // workspace layout: cw 128KB + Q 25.6MB + KV 25.6MB ≈ 51.4 MB
    float* cw = (float*)d_ws;                   // 128 KB (incl. blobs)
    float* Q  = cw + CW_PAD;                    // N*64 f32 = 25.6 MB
    u32*   KV = (u32*)(Q + (size_t)N_PTS * 64); // N*64 u32 = 25.6 MB

    convert_kernel<<<16, 256, 0, stream>>>(
        x,
        d_in[3],  d_in[4],  d_in[5],  d_in[6],  d_in[7],  d_in[8],
        d_in[9],  d_in[10], d_in[11], d_in[12], d_in[13], d_in[14],
        d_in[15], d_in[16], d_in[17], d_in[18], d_in[19], d_in[20],
        d_in[21], d_in[22], cw);
    qkv_mfma_kernel<<<1250, 256, 0, stream>>>(x, cw, Q, KV);  // 1250*5*16 = 100000
    attn_kernel<<<N_PTS / 4, 256, 0, stream>>>(p, idx, x, cw, Q, KV, d_out);
}